// Round 11
// baseline (455.615 us; speedup 1.0000x reference)
//
#include <hip/hip_runtime.h>
#include <math.h>

#define DIM 1024
#define NH 16
#define HD 64
#define BATCH 4
#define SEQ 4096
#define NTOK (BATCH*SEQ)  // 16384

typedef float f32x4 __attribute__((ext_vector_type(4)));
typedef short bf16x8 __attribute__((ext_vector_type(8)));

// LDS dest must be WAVE-UNIFORM base; HW writes base + lane*16B.
#define GLOAD_LDS16(gp, lp)                                                    \
  __builtin_amdgcn_global_load_lds(                                            \
      (const __attribute__((address_space(1))) unsigned int*)(gp),             \
      (__attribute__((address_space(3))) unsigned int*)(lp), 16, 0, 0)

__device__ __forceinline__ unsigned short f2bf(float f) {
  unsigned u = __float_as_uint(f);
  unsigned r = (u + 0x7fffu + ((u >> 16) & 1u)) >> 16;
  return (unsigned short)r;
}
__device__ __forceinline__ float bf2f(unsigned short s) {
  return __uint_as_float((unsigned)s << 16);
}

// ---------------------------------------------------------------------------
// 256x256 bf16 GEMM — R5's proven 4-slot / (512,2) schedule, one output
// matrix per launch (256 blocks = 64 mi x 4 nq). nbase selects the 4-row
// group in the concat B (Q:0 K:4 V:8; O-proj:0 of wob).
//   C = A[16384,1024] @ B[.,1024]^T + bias ; FUSE_FM: Performer feature map
//   out = exp((C@R)/8 - ||C||^2/128) per 64-col head span (wave span==head).
// K-loop (R5, verified 124us/768blk): 4-slot LDS ring (128KB), prefetch
// depth 3, counted vmcnt(8) per K-half (tail 4->0), raw s_barrier, inline-
// asm ds_read_b128 (keeps compiler waitcnt pass out), setprio around MFMA.
// RAW: DSR(h+1) after {VMW(8) -> barrier}: every wave retired its stage(h+1)
// before the barrier -> slot resident. WAR: STG(h+3) into slot (h-1)&3 after
// all reads of it retired (lgkm0 before preceding barriers).
// NOTE __launch_bounds__(512,2): (512,4) caps VGPR at 64 < acc's 128 ->
// accumulator spills to scratch -> 4.8GB HBM, 10x slower (R8 post-mortem).
// ---------------------------------------------------------------------------
template <int OUT_BF16, int FUSE_FM>
__global__ __launch_bounds__(512, 2) void gemm256(
    const unsigned short* __restrict__ A,
    const unsigned short* __restrict__ B,
    const float* __restrict__ bias_g,
    void* __restrict__ Cout,
    const float* __restrict__ Rg, int nbase)
{
    // [0..32768) shorts: A slots 0..3 ; [32768..65536): B slots 0..3 (128KB)
    // FM epilogue: wlds = 8 waves x 4608 reuses [0,36864); Rt at [36864,41472)
    __shared__ __align__(16) unsigned short LDSU[65536];
    const int t    = threadIdx.x;
    const int lane = t & 63;
    const int w    = t >> 6;

    // bijective XCD swizzle (gridDim.x == 256, %8==0)
    const int cpx = gridDim.x >> 3;
    const int swz = (blockIdx.x & 7) * cpx + (blockIdx.x >> 3);
    const int mi  = swz >> 2;                    // 0..63
    const int nq  = swz & 3;                     // 0..3 within this matrix
    const int m0  = mi * 256;
    const int n0g = (nbase + nq) * 256;          // row into concat B
    const int n0  = nq * 256;                    // col into this output

    const int wm = (w >> 2) * 128;
    const int wn = (w & 3) * 64;

    // staging: thread t -> row t>>2 (+128*j), global k-seg (t&3)^((t>>3)&3)
    // stored at LDS chunk t&3   [(t>>3)&3 == (row>>1)&3, j-independent]
    const int srow = t >> 2;
    const int sseg = ((t & 3) ^ ((t >> 3) & 3)) * 8;
    const unsigned short* Ag = A + (size_t)(m0 + srow) * 1024 + sseg;
    const unsigned short* Bg = B + (size_t)(n0g + srow) * 1024 + sseg;
    const int ldst = w * 512;                    // wave-uniform LDS base

    // fragment read: row fr's k-chunk q8 sits at LDS chunk q8^((fr>>1)&3)
    const int fr = lane & 15;
    const int fq = ((lane >> 4) ^ ((fr >> 1) & 3)) * 8;

    // per-lane LDS byte bases for asm ds_read (compile-time offset: rest)
    const unsigned lbase = (unsigned)(size_t)
        (__attribute__((address_space(3))) unsigned short*)&LDSU[0];
    const unsigned abase = lbase + (unsigned)(((wm + fr) * 32 + fq) * 2);
    const unsigned bbase = lbase + 65536u + (unsigned)(((wn + fr) * 32 + fq) * 2);

    f32x4 acc[8][4] = {};
    bf16x8 a1[4], a2[4], bb[2][4];

#define STGA(k, j)                                                            \
  GLOAD_LDS16(Ag + (size_t)(j) * 131072 + (size_t)(k) * 32,                   \
              &LDSU[((k) & 3) * 8192 + (j) * 4096 + ldst])
#define STGB(k, j)                                                            \
  GLOAD_LDS16(Bg + (size_t)(j) * 131072 + (size_t)(k) * 32,                   \
              &LDSU[32768 + ((k) & 3) * 8192 + (j) * 4096 + ldst])
// asm ds_read_b128: base VGPR + compile-time immediate offset
#define DSR(dst, base, imm)                                                   \
  asm volatile("ds_read_b128 %0, %1 offset:%2"                                \
               : "=v"(dst) : "v"(base), "i"(imm))
#define VMW_(N) asm volatile("s_waitcnt vmcnt(" #N ")" ::: "memory")
#define VMW(N) VMW_(N)
#define LGKM0                                                                 \
  asm volatile("s_waitcnt lgkmcnt(0)" ::: "memory");                          \
  __builtin_amdgcn_sched_barrier(0)
#define BARRIER                                                               \
  __builtin_amdgcn_s_barrier();                                               \
  __builtin_amdgcn_sched_barrier(0)

#define BODY(h, VM, DOSTG, DORD)                                              \
  {                                                                           \
    LGKM0;                                                                    \
    _Pragma("unroll")                                                         \
    for (int mf = 0; mf < 4; ++mf)                                            \
      DSR(a2[mf], abase, ((h) & 3) * 16384 + 4096 + mf * 1024);               \
    if (DOSTG) {                                                              \
      STGA((h) + 3, 0); STGA((h) + 3, 1);                                     \
      STGB((h) + 3, 0); STGB((h) + 3, 1);                                     \
    }                                                                         \
    __builtin_amdgcn_s_setprio(1);                                            \
    _Pragma("unroll")                                                         \
    for (int mf = 0; mf < 4; ++mf)                                            \
      _Pragma("unroll")                                                       \
      for (int nf = 0; nf < 4; ++nf)                                          \
        acc[mf][nf] = __builtin_amdgcn_mfma_f32_16x16x32_bf16(                \
            a1[mf], bb[(h) & 1][nf], acc[mf][nf], 0, 0, 0);                   \
    __builtin_amdgcn_s_setprio(0);                                            \
    VMW(VM);                                                                  \
    BARRIER;                                                                  \
    LGKM0;                                                                    \
    if (DORD) {                                                               \
      _Pragma("unroll")                                                       \
      for (int nf = 0; nf < 4; ++nf)                                          \
        DSR(bb[((h) + 1) & 1][nf], bbase,                                     \
            (((h) + 1) & 3) * 16384 + nf * 1024);                             \
      _Pragma("unroll")                                                       \
      for (int mf = 0; mf < 4; ++mf)                                          \
        DSR(a1[mf], abase, (((h) + 1) & 3) * 16384 + mf * 1024);              \
    }                                                                         \
    __builtin_amdgcn_s_setprio(1);                                            \
    _Pragma("unroll")                                                         \
    for (int mf = 0; mf < 4; ++mf)                                            \
      _Pragma("unroll")                                                       \
      for (int nf = 0; nf < 4; ++nf)                                          \
        acc[4 + mf][nf] = __builtin_amdgcn_mfma_f32_16x16x32_bf16(            \
            a2[mf], bb[(h) & 1][nf], acc[4 + mf][nf], 0, 0, 0);               \
    __builtin_amdgcn_s_setprio(0);                                            \
    BARRIER;                                                                  \
  }

    // ---- prologue: stage K-halves 0,1,2 (12 loads in flight) ----
    STGA(0, 0); STGA(0, 1); STGB(0, 0); STGB(0, 1);
    STGA(1, 0); STGA(1, 1); STGB(1, 0); STGB(1, 1);
    STGA(2, 0); STGA(2, 1); STGB(2, 0); STGB(2, 1);
    VMW(8);               // own slot-0 loads retired
    BARRIER;              // all waves' slot-0 loads retired
#pragma unroll
    for (int nf = 0; nf < 4; ++nf)
        DSR(bb[0][nf], bbase, nf * 1024);
#pragma unroll
    for (int mf = 0; mf < 4; ++mf)
        DSR(a1[mf], abase, mf * 1024);

    // ---- main: 32 K-halves, fully unrolled, compile-time slots ----
    BODY(0, 8, 1, 1)  BODY(1, 8, 1, 1)  BODY(2, 8, 1, 1)  BODY(3, 8, 1, 1)
    BODY(4, 8, 1, 1)  BODY(5, 8, 1, 1)  BODY(6, 8, 1, 1)  BODY(7, 8, 1, 1)
    BODY(8, 8, 1, 1)  BODY(9, 8, 1, 1)  BODY(10, 8, 1, 1) BODY(11, 8, 1, 1)
    BODY(12, 8, 1, 1) BODY(13, 8, 1, 1) BODY(14, 8, 1, 1) BODY(15, 8, 1, 1)
    BODY(16, 8, 1, 1) BODY(17, 8, 1, 1) BODY(18, 8, 1, 1) BODY(19, 8, 1, 1)
    BODY(20, 8, 1, 1) BODY(21, 8, 1, 1) BODY(22, 8, 1, 1) BODY(23, 8, 1, 1)
    BODY(24, 8, 1, 1) BODY(25, 8, 1, 1) BODY(26, 8, 1, 1) BODY(27, 8, 1, 1)
    BODY(28, 8, 1, 1) BODY(29, 4, 0, 1) BODY(30, 0, 0, 1) BODY(31, 0, 0, 0)

#undef BODY
#undef BARRIER
#undef LGKM0
#undef VMW
#undef VMW_
#undef DSR
#undef STGB
#undef STGA

    const int col = lane & 15;
    const int rq  = (lane >> 4) * 4;

    if (FUSE_FM) {
        // ---- fused Performer feature map: wave's 64 cols == one head ----
        // stage Rt (transposed R, bf16) at LDSU[36864..41472)
        for (int i = t; i < 4096; i += 512) {
            int n2 = i >> 6, k2 = i & 63;
            LDSU[36864 + n2 * 72 + k2] = f2bf(Rg[k2 * 64 + n2]);
        }
        asm volatile("s_waitcnt lgkmcnt(0)" ::: "memory");
        __builtin_amdgcn_s_barrier();

        unsigned short* wlds = &LDSU[w * 4608];   // wave-private 64x72 bf16
        const int fq0 = (lane >> 4) * 8;          // linear (unswizzled) phase
        const int hcol0 = n0 + wn;                // head col base (64-aligned)
        float bv4[4];
#pragma unroll
        for (int nf = 0; nf < 4; ++nf) bv4[nf] = bias_g[hcol0 + nf * 16 + col];

#pragma unroll
        for (int p = 0; p < 2; ++p) {             // two 64-row passes
            float s4[4][4];
#pragma unroll
            for (int mfl = 0; mfl < 4; ++mfl)
#pragma unroll
                for (int r = 0; r < 4; ++r) s4[mfl][r] = 0.f;
            // bias-add, row-sq-norm partials, LDS transpose (bf16)
#pragma unroll
            for (int mfl = 0; mfl < 4; ++mfl)
#pragma unroll
                for (int nf = 0; nf < 4; ++nf)
#pragma unroll
                    for (int r = 0; r < 4; ++r) {
                        float val = acc[p * 4 + mfl][nf][r] + bv4[nf];
                        s4[mfl][r] = fmaf(val, val, s4[mfl][r]);
                        wlds[(mfl * 16 + rq + r) * 72 + nf * 16 + col] = f2bf(val);
                    }
            // reduce over the 16 col-lanes of each row group
#pragma unroll
            for (int mfl = 0; mfl < 4; ++mfl)
#pragma unroll
                for (int r = 0; r < 4; ++r) {
                    s4[mfl][r] += __shfl_xor(s4[mfl][r], 1);
                    s4[mfl][r] += __shfl_xor(s4[mfl][r], 2);
                    s4[mfl][r] += __shfl_xor(s4[mfl][r], 4);
                    s4[mfl][r] += __shfl_xor(s4[mfl][r], 8);
                }
            // proj = val @ R  (A-frags from wlds, B-frags from Rt)
            f32x4 pr[4][4] = {};
#pragma unroll
            for (int ks = 0; ks < 2; ++ks) {
                bf16x8 bfr[4];
#pragma unroll
                for (int nt = 0; nt < 4; ++nt)
                    bfr[nt] = *(const bf16x8*)
                        &LDSU[36864 + (nt * 16 + fr) * 72 + ks * 32 + fq0];
#pragma unroll
                for (int mfl = 0; mfl < 4; ++mfl) {
                    bf16x8 af = *(const bf16x8*)
                        &wlds[(mfl * 16 + fr) * 72 + ks * 32 + fq0];
#pragma unroll
                    for (int nt = 0; nt < 4; ++nt)
                        pr[mfl][nt] = __builtin_amdgcn_mfma_f32_16x16x32_bf16(
                            af, bfr[nt], pr[mfl][nt], 0, 0, 0);
                }
            }
            // out = exp(proj/8 - sqnorm/128), store bf16
#pragma unroll
            for (int mfl = 0; mfl < 4; ++mfl)
#pragma unroll
                for (int r = 0; r < 4; ++r) {
                    float ss = s4[mfl][r] * 0.0078125f;
                    size_t row = (size_t)(m0 + wm + p * 64 + mfl * 16 + rq + r);
#pragma unroll
                    for (int nt = 0; nt < 4; ++nt) {
                        float e = __expf(pr[mfl][nt][r] * 0.125f - ss);
                        ((unsigned short*)Cout)[row * 1024 + hcol0 + nt * 16 + col]
                            = f2bf(e);
                    }
                }
            // pass-1 frag reads must retire before pass-2 overwrites wlds
            if (p == 0) asm volatile("s_waitcnt lgkmcnt(0)" ::: "memory");
        }
    } else {
        // ---- plain epilogue (V piece, O-proj) ----
#pragma unroll
        for (int nf = 0; nf < 4; ++nf) {
            int cbase = n0 + wn + nf * 16 + col;
            float bv = bias_g[cbase];
#pragma unroll
            for (int mf = 0; mf < 8; ++mf) {
                int rbase = m0 + wm + (mf >> 2) * 64 + (mf & 3) * 16 + rq;
#pragma unroll
                for (int r = 0; r < 4; ++r) {
                    float val = acc[mf][nf][r] + bv;
                    size_t idx = (size_t)(rbase + r) * 1024 + cbase;
                    if (OUT_BF16)
                        ((unsigned short*)Cout)[idx] = f2bf(val);
                    else
                        ((float*)Cout)[idx] = val;
                }
            }
        }
    }
}

// ---------------------------------------------------------------------------
// single fused fp32 -> bf16 cast: x (16M) + Wq/Wk/Wv (->wqkv) + Wo (->wob)
// ---------------------------------------------------------------------------
__global__ __launch_bounds__(256) void cast_all(
    const float* __restrict__ x,  const float* __restrict__ Wq,
    const float* __restrict__ Wk, const float* __restrict__ Wv,
    const float* __restrict__ Wo,
    unsigned short* __restrict__ xb, unsigned short* __restrict__ wqkv,
    unsigned short* __restrict__ wob)
{
    const size_t NX = (size_t)NTOK * DIM;   // 16M
    const size_t NW = (size_t)DIM * DIM;    // 1M
    size_t i = ((size_t)blockIdx.x * 256 + threadIdx.x) * 4;
    const float* s; unsigned short* d; size_t off;
    if (i < NX)               { s = x;  d = xb;             off = i; }
    else if (i < NX + NW)     { s = Wq; d = wqkv;           off = i - NX; }
    else if (i < NX + 2 * NW) { s = Wk; d = wqkv + NW;      off = i - NX - NW; }
    else if (i < NX + 3 * NW) { s = Wv; d = wqkv + 2 * NW;  off = i - NX - 2 * NW; }
    else                      { s = Wo; d = wob;            off = i - NX - 3 * NW; }
    float4 v = *(const float4*)&s[off];
    ushort2 lo = {f2bf(v.x), f2bf(v.y)};
    ushort2 hi = {f2bf(v.z), f2bf(v.w)};
    *(ushort2*)&d[off] = lo;
    *(ushort2*)&d[off + 2] = hi;
}

// ---------------------------------------------------------------------------
// MFMA kv accumulation: kv[b,h,m,e] += sum_n k'[n,m] * v[n,e], 512-tok chunk.
// Staging/fragments as R10 (row-major [256][72], swizzled columns, per-lane
// column reads). R10 post-mortem: duration was pinned by the ATOMIC epilogue
// (8.4M device-scope f32 atomicAdds -> WRITE_SIZE 32.8MB for a 1MB output;
// Mfma/VALU/HBM all <16% = serialization). Fix: cross-wave reduction in LDS
// first. After the K-loop the staging LDS is dead (syncthreads-retired);
// each wave writes its 64x64 f32 partial at red[w*4352 + row*68 + col]
// (row pad 68: quarters land bank-phase 0/16 -> 2-way = free), syncthreads,
// then each thread sums the 4 waves for its 16 outputs and issues ONE
// coalesced atomicAdd per output: 4096/block (was 16384), 2.1M total.
// ---------------------------------------------------------------------------
__global__ __launch_bounds__(256) void kv_accum_mfma(
    const unsigned short* __restrict__ kp, const unsigned short* __restrict__ vp,
    float* __restrict__ kv)
{
    __shared__ __align__(16) unsigned short KV[2][256][72];   // 73728 B
    const int t = threadIdx.x;
    const int lane = t & 63;
    const int w = t >> 6;
    const int h = blockIdx.y, b = blockIdx.z;
    const int nbase = b * SEQ + blockIdx.x * 512;
    const int fr = lane & 15;
    const int q  = lane >> 4;
    const int rswz = (q & 1) << 3;       // read-side column XOR

    f32x4 acc[4][4] = {};   // [m-frag(feat)][e-frag]

    for (int rnd = 0; rnd < 2; ++rnd) {
        // stage 256 tokens x 64 feats, ROW-major; ushort4 = contiguous 8B
        // writes (0 conflicts); coalesced 128B global segments.
#pragma unroll
        for (int i = 0; i < 16; ++i) {
            int idx = i * 256 + t;
            int tok = idx >> 4;           // 0..255
            int e0  = (idx & 15) * 4;     // 0..60
            size_t g = (size_t)(nbase + rnd * 256 + tok) * DIM + h * 64 + e0;
            ushort4 kq = *(const ushort4*)&kp[g];
            ushort4 vq = *(const ushort4*)&vp[g];
            int c = e0 ^ (((tok >> 3) & 1) << 3);   // write-side swizzle
            *(ushort4*)&KV[0][tok][c] = kq;
            *(ushort4*)&KV[1][tok][c] = vq;
        }
        __syncthreads();
        // wave w: tokens [w*64, w*64+64) of this round -> 2 MFMA K-steps.
#pragma unroll
        for (int ks = 0; ks < 2; ++ks) {
            const int ksb = w * 64 + ks * 32 + q * 8;
            bf16x8 af[4], bf[4];
#pragma unroll
            for (int mt = 0; mt < 4; ++mt) {
                const int cc = (mt * 16 + fr) ^ rswz;
                bf16x8 a, bv2;
#pragma unroll
                for (int j = 0; j < 8; ++j) {
                    a[j]   = (short)KV[0][ksb + j][cc];
                    bv2[j] = (short)KV[1][ksb + j][cc];
                }
                af[mt] = a;
                bf[mt] = bv2;
            }
#pragma unroll
            for (int mt = 0; mt < 4; ++mt)
#pragma unroll
                for (int nt = 0; nt < 4; ++nt)
                    acc[mt][nt] = __builtin_amdgcn_mfma_f32_16x16x32_bf16(
                        af[mt], bf[nt], acc[mt][nt], 0, 0, 0);
        }
        __syncthreads();
    }

    // ---- cross-wave reduction in LDS (staging LDS dead past last sync) ----
    // red[w][row*68+col], 4 x 4352 f32 = 69632 B <= 73728 B.
    float* red = (float*)&KV[0][0][0];
    const int col = lane & 15;
    const int rq  = (lane >> 4) * 4;
#pragma unroll
    for (int mt = 0; mt < 4; ++mt)
#pragma unroll
        for (int r = 0; r < 4; ++r)
#pragma unroll
            for (int nt = 0; nt < 4; ++nt)
                red[w * 4352 + (mt * 16 + rq + r) * 68 + nt * 16 + col]
                    = acc[mt][nt][r];
    __syncthreads();

    // thread t: 16 outputs, sum 4 waves, ONE coalesced atomicAdd each.
    float* dst = &kv[(size_t)(b * NH + h) * 4096];
#pragma unroll
    for (int j = 0; j < 16; ++j) {
        int i = j * 256 + t;
        int row = i >> 6, c2 = i & 63;
        int o = row * 68 + c2;
        float v = red[o] + red[4352 + o] + red[2 * 4352 + o] + red[3 * 4352 + o];
        atomicAdd(&dst[i], v);
    }
}

// ---------------------------------------------------------------------------
// MFMA attn out: per (b,h), out[n,e] = z[n] * (q'[n,:] @ kv[:,e])
// ---------------------------------------------------------------------------
__global__ __launch_bounds__(256) void attn_out_mfma(
    const unsigned short* __restrict__ qp, const float* __restrict__ kv,
    unsigned short* __restrict__ ob)
{
    __shared__ unsigned short kvT[64 * 72];
    const int t = threadIdx.x;
    const int bh = blockIdx.y;
    const int b = bh >> 4, h = bh & 15;
    const float* kvp = &kv[(size_t)bh * 4096];
    for (int i = t; i < 4096; i += 256) {
        int m = i >> 6, e = i & 63;
        kvT[e * 72 + m] = f2bf(kvp[i]);
    }
    __syncthreads();

    const int lane = t & 63;
    const int w = t >> 6;
    const int rowInSeq = blockIdx.x * 256 + w * 64;
    const int fr = lane & 15;
    const int fq = (lane >> 4) * 8;

    f32x4 acc[4][4] = {};
    float rsum[4] = {0.f, 0.f, 0.f, 0.f};

#pragma unroll
    for (int ks = 0; ks < 2; ks++) {
        bf16x8 bfr[4];
#pragma unroll
        for (int nt = 0; nt < 4; nt++)
            bfr[nt] = *(const bf16x8*)&kvT[(nt * 16 + fr) * 72 + ks * 32 + fq];
#pragma unroll
        for (int mt = 0; mt < 4; mt++) {
            size_t n = (size_t)(b * SEQ + rowInSeq + mt * 16 + fr);
            bf16x8 a = *(const bf16x8*)&qp[n * DIM + h * 64 + ks * 32 + fq];
#pragma unroll
            for (int j = 0; j < 8; j++)
                rsum[mt] += bf2f((unsigned short)a[j]);
#pragma unroll
            for (int nt = 0; nt < 4; nt++)
                acc[mt][nt] = __builtin_amdgcn_mfma_f32_16x16x32_bf16(
                    a, bfr[nt], acc[mt][nt], 0, 0, 0);
        }
    }
#pragma unroll
    for (int mt = 0; mt < 4; mt++) {
        rsum[mt] += __shfl_xor(rsum[mt], 16);
        rsum[mt] += __shfl_xor(rsum[mt], 32);
    }

    const int col = lane & 15;
    const int rq  = (lane >> 4) * 4;
#pragma unroll
    for (int mt = 0; mt < 4; mt++) {
#pragma unroll
        for (int r = 0; r < 4; r++) {
            float s = __shfl(rsum[mt], rq + r);
            float z = 1.f / (s + 1e-8f);
            size_t n = (size_t)(b * SEQ + rowInSeq + mt * 16 + rq + r);
#pragma unroll
            for (int nt = 0; nt < 4; nt++)
                ob[n * DIM + h * 64 + nt * 16 + col] = f2bf(acc[mt][nt][r] * z);
        }
    }
}

extern "C" void kernel_launch(void* const* d_in, const int* in_sizes, int n_in,
                              void* d_out, int out_size, void* d_ws, size_t ws_size,
                              hipStream_t stream) {
    const float* x  = (const float*)d_in[0];
    const float* Wq = (const float*)d_in[1];
    const float* bq = (const float*)d_in[2];
    const float* Wk = (const float*)d_in[3];
    const float* bk = (const float*)d_in[4];
    const float* Wv = (const float*)d_in[5];
    const float* bv = (const float*)d_in[6];
    const float* Wo = (const float*)d_in[7];
    const float* bo = (const float*)d_in[8];
    const float* R  = (const float*)d_in[9];
    float* out = (float*)d_out;

    // workspace — 137 MB.
    char* p = (char*)d_ws;
    unsigned short* xb = (unsigned short*)p; p += (size_t)NTOK * DIM * 2;  // 32MB
    unsigned short* qb = (unsigned short*)p; p += (size_t)NTOK * DIM * 2;  // 32MB
    unsigned short* kb = (unsigned short*)p; p += (size_t)NTOK * DIM * 2;  // 32MB
    unsigned short* vb = (unsigned short*)p; p += (size_t)NTOK * DIM * 2;  // 32MB
    float* kvb = (float*)p;                  p += (size_t)BATCH * NH * HD * HD * 4; // 1MB
    unsigned short* wqkv = (unsigned short*)p; p += (size_t)3 * DIM * DIM * 2; // 6MB contig
    unsigned short* wob  = (unsigned short*)p; p += (size_t)DIM * DIM * 2;     // 2MB

    hipMemsetAsync(kvb, 0, (size_t)BATCH * NH * HD * HD * sizeof(float), stream);

    // single fused cast launch: x + all 4 weight matrices
    cast_all<<<(NTOK * DIM + 4 * DIM * DIM) / (256 * 4), 256, 0, stream>>>(
        x, Wq, Wk, Wv, Wo, xb, wqkv, wob);

    // QKV projection split into its 3 natural 256-block pieces (one output
    // matrix each; 768 blocks at 1 blk/CU run as 3 full waves anyway).
    // Q and K get the fused Performer feature map; V is a plain GEMM.
    gemm256<1, 1><<<256, 512, 0, stream>>>(xb, wqkv, bq, qb, R, 0);
    gemm256<1, 1><<<256, 512, 0, stream>>>(xb, wqkv, bk, kb, R, 4);
    gemm256<1, 0><<<256, 512, 0, stream>>>(xb, wqkv, bv, vb, nullptr, 8);

    kv_accum_mfma<<<dim3(8, NH, BATCH), 256, 0, stream>>>(kb, vb, kvb);

    // attn output reuses xb
    attn_out_mfma<<<dim3(SEQ / 256, BATCH * NH), 256, 0, stream>>>(qb, kvb, xb);

    // output projection: 256 blocks, fp32 out
    gemm256<0, 0><<<256, 512, 0, stream>>>(xb, wob, bo, out, nullptr, 0);
}

// Round 12
// 338.370 us; speedup vs baseline: 1.3465x; 1.3465x over previous
//
#include <hip/hip_runtime.h>
#include <math.h>

#define DIM 1024
#define NH 16
#define HD 64
#define BATCH 4
#define SEQ 4096
#define NTOK (BATCH*SEQ)  // 16384

typedef float f32x4 __attribute__((ext_vector_type(4)));
typedef short bf16x8 __attribute__((ext_vector_type(8)));

// LDS dest must be WAVE-UNIFORM base; HW writes base + lane*16B.
#define GLOAD_LDS16(gp, lp)                                                    \
  __builtin_amdgcn_global_load_lds(                                            \
      (const __attribute__((address_space(1))) unsigned int*)(gp),             \
      (__attribute__((address_space(3))) unsigned int*)(lp), 16, 0, 0)

__device__ __forceinline__ unsigned short f2bf(float f) {
  unsigned u = __float_as_uint(f);
  unsigned r = (u + 0x7fffu + ((u >> 16) & 1u)) >> 16;
  return (unsigned short)r;
}
__device__ __forceinline__ float bf2f(unsigned short s) {
  return __uint_as_float((unsigned)s << 16);
}

// ---------------------------------------------------------------------------
// 256x256 bf16 GEMM (R5-verified: 124us for the fused 768-block QKV) +
// FUSED Performer feature map in the epilogue for q/k blocks.
//   C = A[16384,1024] @ B[NT_N*256,1024]^T + bias ; then (q,k only)
//   out = exp((C@R)/8 - ||C||^2/128) per 64-col head span (wave span==head).
// K-loop: 4-slot LDS ring (128KB), prefetch depth 3, counted vmcnt(8) per
// K-half (tail 4->0), raw s_barrier, inline-asm ds_read_b128 (keeps the
// compiler waitcnt pass out), setprio around MFMA, chunk-XOR swizzle.
// RAW: DSR(h+1) after {VMW(8) -> barrier}: every wave retired its stage(h+1)
// before the barrier -> slot resident. WAR: STG(h+3) into slot (h-1)&3 after
// all reads of it retired (lgkm0 before preceding barriers).
// NOTE __launch_bounds__(512,2): (512,4) caps VGPR at 64 < acc's 128 ->
// accumulator spills to scratch -> 4.8GB HBM, 10x slower (R8 post-mortem).
// ---------------------------------------------------------------------------
template <int NT_N, int OUT_BF16, int FUSE_FM>
__global__ __launch_bounds__(512, 2) void gemm256(
    const unsigned short* __restrict__ A,
    const unsigned short* __restrict__ B,
    const float* __restrict__ b0, const float* __restrict__ b1,
    const float* __restrict__ b2,
    void* __restrict__ C0, void* __restrict__ C1, void* __restrict__ C2,
    const float* __restrict__ Rg)
{
    // [0..32768) shorts: A slots 0..3 ; [32768..65536): B slots 0..3 (128KB)
    // FM epilogue: wlds = 8 waves x 4608 reuses [0,36864); Rt at [36864,41472)
    __shared__ __align__(16) unsigned short LDSU[65536];
    const int t    = threadIdx.x;
    const int lane = t & 63;
    const int w    = t >> 6;

    // bijective XCD swizzle (nwg % 8 == 0 for both grids)
    const int cpx = gridDim.x >> 3;
    const int swz = (blockIdx.x & 7) * cpx + (blockIdx.x >> 3);
    const int mi  = swz / NT_N;
    const int ni  = swz % NT_N;
    const int m0  = mi * 256;
    const int n0g = ni * 256;                    // row into concat B

    const int wm = (w >> 2) * 128;
    const int wn = (w & 3) * 64;

    // staging: thread t -> row t>>2 (+128*j), global k-seg (t&3)^((t>>3)&3)
    // stored at LDS chunk t&3   [(t>>3)&3 == (row>>1)&3, j-independent]
    const int srow = t >> 2;
    const int sseg = ((t & 3) ^ ((t >> 3) & 3)) * 8;
    const unsigned short* Ag = A + (size_t)(m0 + srow) * 1024 + sseg;
    const unsigned short* Bg = B + (size_t)(n0g + srow) * 1024 + sseg;
    const int ldst = w * 512;                    // wave-uniform LDS base

    // fragment read: row fr's k-chunk q8 sits at LDS chunk q8^((fr>>1)&3)
    const int fr = lane & 15;
    const int fq = ((lane >> 4) ^ ((fr >> 1) & 3)) * 8;

    // per-lane LDS byte bases for asm ds_read (compile-time offset: rest)
    const unsigned lbase = (unsigned)(size_t)
        (__attribute__((address_space(3))) unsigned short*)&LDSU[0];
    const unsigned abase = lbase + (unsigned)(((wm + fr) * 32 + fq) * 2);
    const unsigned bbase = lbase + 65536u + (unsigned)(((wn + fr) * 32 + fq) * 2);

    f32x4 acc[8][4] = {};
    bf16x8 a1[4], a2[4], bb[2][4];

#define STGA(k, j)                                                            \
  GLOAD_LDS16(Ag + (size_t)(j) * 131072 + (size_t)(k) * 32,                   \
              &LDSU[((k) & 3) * 8192 + (j) * 4096 + ldst])
#define STGB(k, j)                                                            \
  GLOAD_LDS16(Bg + (size_t)(j) * 131072 + (size_t)(k) * 32,                   \
              &LDSU[32768 + ((k) & 3) * 8192 + (j) * 4096 + ldst])
// asm ds_read_b128: base VGPR + compile-time immediate offset
#define DSR(dst, base, imm)                                                   \
  asm volatile("ds_read_b128 %0, %1 offset:%2"                                \
               : "=v"(dst) : "v"(base), "i"(imm))
#define VMW_(N) asm volatile("s_waitcnt vmcnt(" #N ")" ::: "memory")
#define VMW(N) VMW_(N)
#define LGKM0                                                                 \
  asm volatile("s_waitcnt lgkmcnt(0)" ::: "memory");                          \
  __builtin_amdgcn_sched_barrier(0)
#define BARRIER                                                               \
  __builtin_amdgcn_s_barrier();                                               \
  __builtin_amdgcn_sched_barrier(0)

#define BODY(h, VM, DOSTG, DORD)                                              \
  {                                                                           \
    LGKM0;                                                                    \
    _Pragma("unroll")                                                         \
    for (int mf = 0; mf < 4; ++mf)                                            \
      DSR(a2[mf], abase, ((h) & 3) * 16384 + 4096 + mf * 1024);               \
    if (DOSTG) {                                                              \
      STGA((h) + 3, 0); STGA((h) + 3, 1);                                     \
      STGB((h) + 3, 0); STGB((h) + 3, 1);                                     \
    }                                                                         \
    __builtin_amdgcn_s_setprio(1);                                            \
    _Pragma("unroll")                                                         \
    for (int mf = 0; mf < 4; ++mf)                                            \
      _Pragma("unroll")                                                       \
      for (int nf = 0; nf < 4; ++nf)                                          \
        acc[mf][nf] = __builtin_amdgcn_mfma_f32_16x16x32_bf16(                \
            a1[mf], bb[(h) & 1][nf], acc[mf][nf], 0, 0, 0);                   \
    __builtin_amdgcn_s_setprio(0);                                            \
    VMW(VM);                                                                  \
    BARRIER;                                                                  \
    LGKM0;                                                                    \
    if (DORD) {                                                               \
      _Pragma("unroll")                                                       \
      for (int nf = 0; nf < 4; ++nf)                                          \
        DSR(bb[((h) + 1) & 1][nf], bbase,                                     \
            (((h) + 1) & 3) * 16384 + nf * 1024);                             \
      _Pragma("unroll")                                                       \
      for (int mf = 0; mf < 4; ++mf)                                          \
        DSR(a1[mf], abase, (((h) + 1) & 3) * 16384 + mf * 1024);              \
    }                                                                         \
    __builtin_amdgcn_s_setprio(1);                                            \
    _Pragma("unroll")                                                         \
    for (int mf = 0; mf < 4; ++mf)                                            \
      _Pragma("unroll")                                                       \
      for (int nf = 0; nf < 4; ++nf)                                          \
        acc[4 + mf][nf] = __builtin_amdgcn_mfma_f32_16x16x32_bf16(            \
            a2[mf], bb[(h) & 1][nf], acc[4 + mf][nf], 0, 0, 0);               \
    __builtin_amdgcn_s_setprio(0);                                            \
    BARRIER;                                                                  \
  }

    // ---- prologue: stage K-halves 0,1,2 (12 loads in flight) ----
    STGA(0, 0); STGA(0, 1); STGB(0, 0); STGB(0, 1);
    STGA(1, 0); STGA(1, 1); STGB(1, 0); STGB(1, 1);
    STGA(2, 0); STGA(2, 1); STGB(2, 0); STGB(2, 1);
    VMW(8);               // own slot-0 loads retired
    BARRIER;              // all waves' slot-0 loads retired
#pragma unroll
    for (int nf = 0; nf < 4; ++nf)
        DSR(bb[0][nf], bbase, nf * 1024);
#pragma unroll
    for (int mf = 0; mf < 4; ++mf)
        DSR(a1[mf], abase, mf * 1024);

    // ---- main: 32 K-halves, fully unrolled, compile-time slots ----
    BODY(0, 8, 1, 1)  BODY(1, 8, 1, 1)  BODY(2, 8, 1, 1)  BODY(3, 8, 1, 1)
    BODY(4, 8, 1, 1)  BODY(5, 8, 1, 1)  BODY(6, 8, 1, 1)  BODY(7, 8, 1, 1)
    BODY(8, 8, 1, 1)  BODY(9, 8, 1, 1)  BODY(10, 8, 1, 1) BODY(11, 8, 1, 1)
    BODY(12, 8, 1, 1) BODY(13, 8, 1, 1) BODY(14, 8, 1, 1) BODY(15, 8, 1, 1)
    BODY(16, 8, 1, 1) BODY(17, 8, 1, 1) BODY(18, 8, 1, 1) BODY(19, 8, 1, 1)
    BODY(20, 8, 1, 1) BODY(21, 8, 1, 1) BODY(22, 8, 1, 1) BODY(23, 8, 1, 1)
    BODY(24, 8, 1, 1) BODY(25, 8, 1, 1) BODY(26, 8, 1, 1) BODY(27, 8, 1, 1)
    BODY(28, 8, 1, 1) BODY(29, 4, 0, 1) BODY(30, 0, 0, 1) BODY(31, 0, 0, 0)

#undef BODY
#undef BARRIER
#undef LGKM0
#undef VMW
#undef VMW_
#undef DSR
#undef STGB
#undef STGA

    // matrix select (uniform per block); C/D layout col=lane&15,
    // row=(lane>>4)*4+r
    const int mat = ni >> 2;
    const float* bias = (NT_N == 4) ? b0 : (mat == 0 ? b0 : mat == 1 ? b1 : b2);
    void* Cp = (NT_N == 4) ? C0 : (mat == 0 ? C0 : mat == 1 ? C1 : C2);
    const int n0 = (NT_N == 4) ? ni * 256 : (ni & 3) * 256;
    const int col = lane & 15;
    const int rq  = (lane >> 4) * 4;

    if (FUSE_FM && mat < 2) {
        // ---- fused Performer feature map: wave's 64 cols == one head ----
        // stage Rt (transposed R, bf16) at LDSU[36864..41472)
        for (int i = t; i < 4096; i += 512) {
            int n2 = i >> 6, k2 = i & 63;
            LDSU[36864 + n2 * 72 + k2] = f2bf(Rg[k2 * 64 + n2]);
        }
        asm volatile("s_waitcnt lgkmcnt(0)" ::: "memory");
        __builtin_amdgcn_s_barrier();

        unsigned short* wlds = &LDSU[w * 4608];   // wave-private 64x72 bf16
        const int fq0 = (lane >> 4) * 8;          // linear (unswizzled) phase
        const int hcol0 = n0 + wn;                // head col base (64-aligned)
        float bv4[4];
#pragma unroll
        for (int nf = 0; nf < 4; ++nf) bv4[nf] = bias[hcol0 + nf * 16 + col];

#pragma unroll
        for (int p = 0; p < 2; ++p) {             // two 64-row passes
            float s4[4][4];
#pragma unroll
            for (int mfl = 0; mfl < 4; ++mfl)
#pragma unroll
                for (int r = 0; r < 4; ++r) s4[mfl][r] = 0.f;
            // bias-add, row-sq-norm partials, LDS transpose (bf16)
#pragma unroll
            for (int mfl = 0; mfl < 4; ++mfl)
#pragma unroll
                for (int nf = 0; nf < 4; ++nf)
#pragma unroll
                    for (int r = 0; r < 4; ++r) {
                        float val = acc[p * 4 + mfl][nf][r] + bv4[nf];
                        s4[mfl][r] = fmaf(val, val, s4[mfl][r]);
                        wlds[(mfl * 16 + rq + r) * 72 + nf * 16 + col] = f2bf(val);
                    }
            // reduce over the 16 col-lanes of each row group
#pragma unroll
            for (int mfl = 0; mfl < 4; ++mfl)
#pragma unroll
                for (int r = 0; r < 4; ++r) {
                    s4[mfl][r] += __shfl_xor(s4[mfl][r], 1);
                    s4[mfl][r] += __shfl_xor(s4[mfl][r], 2);
                    s4[mfl][r] += __shfl_xor(s4[mfl][r], 4);
                    s4[mfl][r] += __shfl_xor(s4[mfl][r], 8);
                }
            // proj = val @ R  (A-frags from wlds, B-frags from Rt)
            f32x4 pr[4][4] = {};
#pragma unroll
            for (int ks = 0; ks < 2; ++ks) {
                bf16x8 bfr[4];
#pragma unroll
                for (int nt = 0; nt < 4; ++nt)
                    bfr[nt] = *(const bf16x8*)
                        &LDSU[36864 + (nt * 16 + fr) * 72 + ks * 32 + fq0];
#pragma unroll
                for (int mfl = 0; mfl < 4; ++mfl) {
                    bf16x8 af = *(const bf16x8*)
                        &wlds[(mfl * 16 + fr) * 72 + ks * 32 + fq0];
#pragma unroll
                    for (int nt = 0; nt < 4; ++nt)
                        pr[mfl][nt] = __builtin_amdgcn_mfma_f32_16x16x32_bf16(
                            af, bfr[nt], pr[mfl][nt], 0, 0, 0);
                }
            }
            // out = exp(proj/8 - sqnorm/128), store bf16
#pragma unroll
            for (int mfl = 0; mfl < 4; ++mfl)
#pragma unroll
                for (int r = 0; r < 4; ++r) {
                    float ss = s4[mfl][r] * 0.0078125f;
                    size_t row = (size_t)(m0 + wm + p * 64 + mfl * 16 + rq + r);
#pragma unroll
                    for (int nt = 0; nt < 4; ++nt) {
                        float e = __expf(pr[mfl][nt][r] * 0.125f - ss);
                        ((unsigned short*)Cp)[row * 1024 + hcol0 + nt * 16 + col]
                            = f2bf(e);
                    }
                }
            // pass-1 frag reads must retire before pass-2 overwrites wlds
            if (p == 0) asm volatile("s_waitcnt lgkmcnt(0)" ::: "memory");
        }
    } else {
        // ---- plain epilogue (v blocks, O-proj) ----
#pragma unroll
        for (int nf = 0; nf < 4; ++nf) {
            int cbase = n0 + wn + nf * 16 + col;
            float bv = bias[cbase];
#pragma unroll
            for (int mf = 0; mf < 8; ++mf) {
                int rbase = m0 + wm + (mf >> 2) * 64 + (mf & 3) * 16 + rq;
#pragma unroll
                for (int r = 0; r < 4; ++r) {
                    float val = acc[mf][nf][r] + bv;
                    size_t idx = (size_t)(rbase + r) * 1024 + cbase;
                    if (OUT_BF16)
                        ((unsigned short*)Cp)[idx] = f2bf(val);
                    else
                        ((float*)Cp)[idx] = val;
                }
            }
        }
    }
}

// ---------------------------------------------------------------------------
// single fused fp32 -> bf16 cast: x (16M) + Wq/Wk/Wv (->wqkv) + Wo (->wob)
// ---------------------------------------------------------------------------
__global__ __launch_bounds__(256) void cast_all(
    const float* __restrict__ x,  const float* __restrict__ Wq,
    const float* __restrict__ Wk, const float* __restrict__ Wv,
    const float* __restrict__ Wo,
    unsigned short* __restrict__ xb, unsigned short* __restrict__ wqkv,
    unsigned short* __restrict__ wob)
{
    const size_t NX = (size_t)NTOK * DIM;   // 16M
    const size_t NW = (size_t)DIM * DIM;    // 1M
    size_t i = ((size_t)blockIdx.x * 256 + threadIdx.x) * 4;
    const float* s; unsigned short* d; size_t off;
    if (i < NX)               { s = x;  d = xb;             off = i; }
    else if (i < NX + NW)     { s = Wq; d = wqkv;           off = i - NX; }
    else if (i < NX + 2 * NW) { s = Wk; d = wqkv + NW;      off = i - NX - NW; }
    else if (i < NX + 3 * NW) { s = Wv; d = wqkv + 2 * NW;  off = i - NX - 2 * NW; }
    else                      { s = Wo; d = wob;            off = i - NX - 3 * NW; }
    float4 v = *(const float4*)&s[off];
    ushort2 lo = {f2bf(v.x), f2bf(v.y)};
    ushort2 hi = {f2bf(v.z), f2bf(v.w)};
    *(ushort2*)&d[off] = lo;
    *(ushort2*)&d[off + 2] = hi;
}

// ---------------------------------------------------------------------------
// MFMA kv accumulation: kv[b,h,m,e] += sum_n k'[n,m] * v[n,e], 512-tok chunk.
// Row-major staging [256][72] (0-conflict ushort4 writes, coalesced loads),
// column-read fragments with tok-group XOR swizzle (2-way = free), and
// (R11) cross-wave LDS reduction before the atomic epilogue: each wave
// writes its 64x64 f32 partial (row pad 68 -> 2-way free), syncthreads,
// each thread sums 4 waves for 16 outputs -> ONE coalesced atomicAdd each:
// 4096/block (was 16384), 2.1M total (was 8.4M; WRITE 32.8 -> ~8.4MB).
// ---------------------------------------------------------------------------
__global__ __launch_bounds__(256) void kv_accum_mfma(
    const unsigned short* __restrict__ kp, const unsigned short* __restrict__ vp,
    float* __restrict__ kv)
{
    __shared__ __align__(16) unsigned short KV[2][256][72];   // 73728 B
    const int t = threadIdx.x;
    const int lane = t & 63;
    const int w = t >> 6;
    const int h = blockIdx.y, b = blockIdx.z;
    const int nbase = b * SEQ + blockIdx.x * 512;
    const int fr = lane & 15;
    const int q  = lane >> 4;
    const int rswz = (q & 1) << 3;       // read-side column XOR

    f32x4 acc[4][4] = {};   // [m-frag(feat)][e-frag]

    for (int rnd = 0; rnd < 2; ++rnd) {
#pragma unroll
        for (int i = 0; i < 16; ++i) {
            int idx = i * 256 + t;
            int tok = idx >> 4;           // 0..255
            int e0  = (idx & 15) * 4;     // 0..60
            size_t g = (size_t)(nbase + rnd * 256 + tok) * DIM + h * 64 + e0;
            ushort4 kq = *(const ushort4*)&kp[g];
            ushort4 vq = *(const ushort4*)&vp[g];
            int c = e0 ^ (((tok >> 3) & 1) << 3);   // write-side swizzle
            *(ushort4*)&KV[0][tok][c] = kq;
            *(ushort4*)&KV[1][tok][c] = vq;
        }
        __syncthreads();
#pragma unroll
        for (int ks = 0; ks < 2; ++ks) {
            const int ksb = w * 64 + ks * 32 + q * 8;
            bf16x8 af[4], bf[4];
#pragma unroll
            for (int mt = 0; mt < 4; ++mt) {
                const int cc = (mt * 16 + fr) ^ rswz;
                bf16x8 a, bv2;
#pragma unroll
                for (int j = 0; j < 8; ++j) {
                    a[j]   = (short)KV[0][ksb + j][cc];
                    bv2[j] = (short)KV[1][ksb + j][cc];
                }
                af[mt] = a;
                bf[mt] = bv2;
            }
#pragma unroll
            for (int mt = 0; mt < 4; ++mt)
#pragma unroll
                for (int nt = 0; nt < 4; ++nt)
                    acc[mt][nt] = __builtin_amdgcn_mfma_f32_16x16x32_bf16(
                        af[mt], bf[nt], acc[mt][nt], 0, 0, 0);
        }
        __syncthreads();
    }

    // ---- cross-wave reduction in LDS (staging LDS dead past last sync) ----
    // red[w][row*68+col], 4 x 4352 f32 = 69632 B <= 73728 B.
    float* red = (float*)&KV[0][0][0];
    const int col = lane & 15;
    const int rq  = (lane >> 4) * 4;
#pragma unroll
    for (int mt = 0; mt < 4; ++mt)
#pragma unroll
        for (int r = 0; r < 4; ++r)
#pragma unroll
            for (int nt = 0; nt < 4; ++nt)
                red[w * 4352 + (mt * 16 + rq + r) * 68 + nt * 16 + col]
                    = acc[mt][nt][r];
    __syncthreads();

    // thread t: 16 outputs, sum 4 waves, ONE coalesced atomicAdd each.
    float* dst = &kv[(size_t)(b * NH + h) * 4096];
#pragma unroll
    for (int j = 0; j < 16; ++j) {
        int i = j * 256 + t;
        int row = i >> 6, c2 = i & 63;
        int o = row * 68 + c2;
        float v = red[o] + red[4352 + o] + red[2 * 4352 + o] + red[3 * 4352 + o];
        atomicAdd(&dst[i], v);
    }
}

// ---------------------------------------------------------------------------
// MFMA attn out: per (b,h), out[n,e] = z[n] * (q'[n,:] @ kv[:,e])
// ---------------------------------------------------------------------------
__global__ __launch_bounds__(256) void attn_out_mfma(
    const unsigned short* __restrict__ qp, const float* __restrict__ kv,
    unsigned short* __restrict__ ob)
{
    __shared__ unsigned short kvT[64 * 72];
    const int t = threadIdx.x;
    const int bh = blockIdx.y;
    const int b = bh >> 4, h = bh & 15;
    const float* kvp = &kv[(size_t)bh * 4096];
    for (int i = t; i < 4096; i += 256) {
        int m = i >> 6, e = i & 63;
        kvT[e * 72 + m] = f2bf(kvp[i]);
    }
    __syncthreads();

    const int lane = t & 63;
    const int w = t >> 6;
    const int rowInSeq = blockIdx.x * 256 + w * 64;
    const int fr = lane & 15;
    const int fq = (lane >> 4) * 8;

    f32x4 acc[4][4] = {};
    float rsum[4] = {0.f, 0.f, 0.f, 0.f};

#pragma unroll
    for (int ks = 0; ks < 2; ks++) {
        bf16x8 bfr[4];
#pragma unroll
        for (int nt = 0; nt < 4; nt++)
            bfr[nt] = *(const bf16x8*)&kvT[(nt * 16 + fr) * 72 + ks * 32 + fq];
#pragma unroll
        for (int mt = 0; mt < 4; mt++) {
            size_t n = (size_t)(b * SEQ + rowInSeq + mt * 16 + fr);
            bf16x8 a = *(const bf16x8*)&qp[n * DIM + h * 64 + ks * 32 + fq];
#pragma unroll
            for (int j = 0; j < 8; j++)
                rsum[mt] += bf2f((unsigned short)a[j]);
#pragma unroll
            for (int nt = 0; nt < 4; nt++)
                acc[mt][nt] = __builtin_amdgcn_mfma_f32_16x16x32_bf16(
                    a, bfr[nt], acc[mt][nt], 0, 0, 0);
        }
    }
#pragma unroll
    for (int mt = 0; mt < 4; mt++) {
        rsum[mt] += __shfl_xor(rsum[mt], 16);
        rsum[mt] += __shfl_xor(rsum[mt], 32);
    }

    const int col = lane & 15;
    const int rq  = (lane >> 4) * 4;
#pragma unroll
    for (int mt = 0; mt < 4; mt++) {
#pragma unroll
        for (int r = 0; r < 4; r++) {
            float s = __shfl(rsum[mt], rq + r);
            float z = 1.f / (s + 1e-8f);
            size_t n = (size_t)(b * SEQ + rowInSeq + mt * 16 + rq + r);
#pragma unroll
            for (int nt = 0; nt < 4; nt++)
                ob[n * DIM + h * 64 + nt * 16 + col] = f2bf(acc[mt][nt][r] * z);
        }
    }
}

extern "C" void kernel_launch(void* const* d_in, const int* in_sizes, int n_in,
                              void* d_out, int out_size, void* d_ws, size_t ws_size,
                              hipStream_t stream) {
    const float* x  = (const float*)d_in[0];
    const float* Wq = (const float*)d_in[1];
    const float* bq = (const float*)d_in[2];
    const float* Wk = (const float*)d_in[3];
    const float* bk = (const float*)d_in[4];
    const float* Wv = (const float*)d_in[5];
    const float* bv = (const float*)d_in[6];
    const float* Wo = (const float*)d_in[7];
    const float* bo = (const float*)d_in[8];
    const float* R  = (const float*)d_in[9];
    float* out = (float*)d_out;

    // workspace — 137 MB.
    char* p = (char*)d_ws;
    unsigned short* xb = (unsigned short*)p; p += (size_t)NTOK * DIM * 2;  // 32MB
    unsigned short* qb = (unsigned short*)p; p += (size_t)NTOK * DIM * 2;  // 32MB
    unsigned short* kb = (unsigned short*)p; p += (size_t)NTOK * DIM * 2;  // 32MB
    unsigned short* vb = (unsigned short*)p; p += (size_t)NTOK * DIM * 2;  // 32MB
    float* kvb = (float*)p;                  p += (size_t)BATCH * NH * HD * HD * 4; // 1MB
    unsigned short* wqkv = (unsigned short*)p; p += (size_t)3 * DIM * DIM * 2; // 6MB contig
    unsigned short* wob  = (unsigned short*)p; p += (size_t)DIM * DIM * 2;     // 2MB

    hipMemsetAsync(kvb, 0, (size_t)BATCH * NH * HD * HD * sizeof(float), stream);

    // single fused cast launch: x + all 4 weight matrices
    cast_all<<<(NTOK * DIM + 4 * DIM * DIM) / (256 * 4), 256, 0, stream>>>(
        x, Wq, Wk, Wv, Wo, xb, wqkv, wob);

    // fused QKV projection + Performer feature map (q,k): 768 blocks
    gemm256<12, 1, 1><<<768, 512, 0, stream>>>(
        xb, wqkv, bq, bk, bv, qb, kb, vb, R);

    kv_accum_mfma<<<dim3(8, NH, BATCH), 256, 0, stream>>>(kb, vb, kvb);

    // attn output reuses xb
    attn_out_mfma<<<dim3(SEQ / 256, BATCH * NH), 256, 0, stream>>>(qb, kvb, xb);

    // output projection: 256 blocks, fp32 out
    gemm256<4, 0, 0><<<256, 512, 0, stream>>>(
        xb, wob, bo, bo, bo, out, out, out, nullptr);
}